// Round 2
// baseline (98.482 us; speedup 1.0000x reference)
//
#include <hip/hip_runtime.h>
#include <math.h>

#define EARLY 1.5f
#define GAP   3.0f
#define LATE  2.0f

#define NBLOCKS 2048
#define NTHREADS 256
#define NWAVES (NTHREADS / 64)

__device__ __forceinline__ float term(float a, float b) {
    float d = b - a;
    float w = (d >= GAP) ? EARLY : ((d < 0.0f) ? LATE : 1.0f);
    float t = d * w;
    return t * t;
}

__device__ __forceinline__ float term4(float4 a, float4 b) {
    return term(a.x, b.x) + term(a.y, b.y) + term(a.z, b.z) + term(a.w, b.w);
}

__global__ __launch_bounds__(NTHREADS) void rmse_fused_kernel(
    const float* __restrict__ in, const float* __restrict__ tg,
    float* __restrict__ out, float* __restrict__ partial,
    unsigned int* __restrict__ counter, int n, float invN)
{
    const int n4 = n >> 2;
    const float4* __restrict__ in4 = (const float4*)in;
    const float4* __restrict__ tg4 = (const float4*)tg;

    const int tid = blockIdx.x * NTHREADS + threadIdx.x;
    const int stride = NBLOCKS * NTHREADS;

    float acc0 = 0.f, acc1 = 0.f, acc2 = 0.f, acc3 = 0.f;
    int i = tid;
    // unroll-by-4: 8 dwordx4 loads in flight per thread, 4 independent acc chains
    for (; i + 3 * stride < n4; i += 4 * stride) {
        float4 a0 = in4[i];              float4 b0 = tg4[i];
        float4 a1 = in4[i + stride];     float4 b1 = tg4[i + stride];
        float4 a2 = in4[i + 2 * stride]; float4 b2 = tg4[i + 2 * stride];
        float4 a3 = in4[i + 3 * stride]; float4 b3 = tg4[i + 3 * stride];
        acc0 += term4(a0, b0);
        acc1 += term4(a1, b1);
        acc2 += term4(a2, b2);
        acc3 += term4(a3, b3);
    }
    for (; i < n4; i += stride)
        acc0 += term4(in4[i], tg4[i]);
    // scalar tail (n % 4)
    for (int j = (n4 << 2) + tid; j < n; j += stride)
        acc1 += term(in[j], tg[j]);

    float acc = (acc0 + acc1) + (acc2 + acc3);

    // wave-64 reduction
    #pragma unroll
    for (int off = 32; off > 0; off >>= 1)
        acc += __shfl_down(acc, off, 64);

    __shared__ float smem[NWAVES];
    const int lane = threadIdx.x & 63;
    const int wid  = threadIdx.x >> 6;
    if (lane == 0) smem[wid] = acc;
    __syncthreads();

    __shared__ bool is_last;
    if (threadIdx.x == 0) {
        float t = 0.f;
        #pragma unroll
        for (int w = 0; w < NWAVES; ++w) t += smem[w];
        partial[blockIdx.x] = t;
        __threadfence();  // device-scope: partial visible before counter bump
        unsigned int old = atomicAdd(counter, 1u);
        is_last = (old == (unsigned int)(gridDim.x - 1));
    }
    __syncthreads();

    if (is_last) {
        __threadfence();
        // last block reduces all partials (fixed order -> deterministic)
        float t = 0.f;
        for (int p = threadIdx.x; p < NBLOCKS; p += NTHREADS) {
            // agent-scope atomic load: bypass stale-cache hazards across XCDs
            t += __hip_atomic_load(&partial[p], __ATOMIC_RELAXED,
                                   __HIP_MEMORY_SCOPE_AGENT);
        }
        #pragma unroll
        for (int off = 32; off > 0; off >>= 1)
            t += __shfl_down(t, off, 64);
        if (lane == 0) smem[wid] = t;
        __syncthreads();
        if (threadIdx.x == 0) {
            float s = 0.f;
            #pragma unroll
            for (int w = 0; w < NWAVES; ++w) s += smem[w];
            out[0] = sqrtf(s * invN);
        }
    }
}

extern "C" void kernel_launch(void* const* d_in, const int* in_sizes, int n_in,
                              void* d_out, int out_size, void* d_ws, size_t ws_size,
                              hipStream_t stream) {
    const float* inputs  = (const float*)d_in[0];
    const float* targets = (const float*)d_in[1];
    float* out = (float*)d_out;
    float* partial = (float*)d_ws;                       // NBLOCKS floats
    unsigned int* counter = (unsigned int*)((char*)d_ws + NBLOCKS * sizeof(float));
    int n = in_sizes[0];

    // reset the completion counter every call (graph-capture safe)
    hipMemsetAsync(counter, 0, sizeof(unsigned int), stream);
    rmse_fused_kernel<<<NBLOCKS, NTHREADS, 0, stream>>>(
        inputs, targets, out, partial, counter, n, 1.0f / (float)n);
}

// Round 3
// 32.323 us; speedup vs baseline: 3.0469x; 3.0469x over previous
//
#include <hip/hip_runtime.h>
#include <math.h>

#define EARLY 1.5f
#define GAP   3.0f
#define LATE  2.0f

#define NBLOCKS 2048
#define NTHREADS 256
#define NWAVES (NTHREADS / 64)

__device__ __forceinline__ float term(float a, float b) {
    float d = b - a;
    float w = (d >= GAP) ? EARLY : ((d < 0.0f) ? LATE : 1.0f);
    float t = d * w;
    return t * t;
}

__device__ __forceinline__ float term4(float4 a, float4 b) {
    return term(a.x, b.x) + term(a.y, b.y) + term(a.z, b.z) + term(a.w, b.w);
}

__global__ __launch_bounds__(NTHREADS) void rmse_partial_kernel(
    const float* __restrict__ in, const float* __restrict__ tg,
    float* __restrict__ partial, int n)
{
    const int n4 = n >> 2;  // number of float4 chunks
    const float4* __restrict__ in4 = (const float4*)in;
    const float4* __restrict__ tg4 = (const float4*)tg;

    const int tid = blockIdx.x * NTHREADS + threadIdx.x;
    const int stride = NBLOCKS * NTHREADS;

    float acc0 = 0.f, acc1 = 0.f;
    // contiguous unroll-by-2: each thread owns float4 pair (2i, 2i+1);
    // 4 independent dwordx4 loads in flight, wave covers 2KB/stream contiguous
    for (int i = 2 * tid; i + 1 < n4; i += 2 * stride) {
        float4 a0 = in4[i];     float4 b0 = tg4[i];
        float4 a1 = in4[i + 1]; float4 b1 = tg4[i + 1];
        acc0 += term4(a0, b0);
        acc1 += term4(a1, b1);
    }
    // odd-n4 leftover float4 (single index n4-1), one thread
    if ((n4 & 1) && tid == 0)
        acc0 += term4(in4[n4 - 1], tg4[n4 - 1]);
    // scalar tail (n % 4)
    for (int j = (n4 << 2) + tid; j < n; j += stride)
        acc1 += term(in[j], tg[j]);

    float acc = acc0 + acc1;

    // wave-64 reduction
    #pragma unroll
    for (int off = 32; off > 0; off >>= 1)
        acc += __shfl_down(acc, off, 64);

    __shared__ float smem[NWAVES];
    const int lane = threadIdx.x & 63;
    const int wid  = threadIdx.x >> 6;
    if (lane == 0) smem[wid] = acc;
    __syncthreads();

    if (threadIdx.x == 0) {
        float t = 0.f;
        #pragma unroll
        for (int w = 0; w < NWAVES; ++w) t += smem[w];
        partial[blockIdx.x] = t;
    }
}

__global__ __launch_bounds__(NTHREADS) void rmse_final_kernel(
    const float* __restrict__ partial, int nb,
    float* __restrict__ out, float invN)
{
    float acc = 0.0f;
    for (int i = threadIdx.x; i < nb; i += blockDim.x)
        acc += partial[i];

    #pragma unroll
    for (int off = 32; off > 0; off >>= 1)
        acc += __shfl_down(acc, off, 64);

    __shared__ float smem[NWAVES];
    const int lane = threadIdx.x & 63;
    const int wid  = threadIdx.x >> 6;
    if (lane == 0) smem[wid] = acc;
    __syncthreads();

    if (threadIdx.x == 0) {
        float t = 0.0f;
        #pragma unroll
        for (int w = 0; w < NWAVES; ++w) t += smem[w];
        out[0] = sqrtf(t * invN);
    }
}

extern "C" void kernel_launch(void* const* d_in, const int* in_sizes, int n_in,
                              void* d_out, int out_size, void* d_ws, size_t ws_size,
                              hipStream_t stream) {
    const float* inputs  = (const float*)d_in[0];
    const float* targets = (const float*)d_in[1];
    float* out = (float*)d_out;
    float* partial = (float*)d_ws;   // NBLOCKS floats, well under ws_size
    int n = in_sizes[0];

    rmse_partial_kernel<<<NBLOCKS, NTHREADS, 0, stream>>>(inputs, targets, partial, n);
    rmse_final_kernel<<<1, NTHREADS, 0, stream>>>(partial, NBLOCKS, out, 1.0f / (float)n);
}

// Round 4
// 30.636 us; speedup vs baseline: 3.2146x; 1.0550x over previous
//
#include <hip/hip_runtime.h>
#include <math.h>

#define EARLY 1.5f
#define GAP   3.0f
#define LATE  2.0f

// 977 blocks x 4 waves = 3908 waves; 19531 wave-tiles / 3908 = 4.9977
// -> near-perfect work balance (ceil-ratio 1.0005 vs 1.048 at 2048 blocks)
#define NBLOCKS 977
#define NTHREADS 256
#define NWAVES (NTHREADS / 64)
#define TOTAL_WAVES (NBLOCKS * NWAVES)
#define TOTAL_THREADS (NBLOCKS * NTHREADS)

__device__ __forceinline__ float term(float a, float b) {
    float d = b - a;
    float w = (d >= GAP) ? EARLY : ((d < 0.0f) ? LATE : 1.0f);
    float t = d * w;
    return t * t;
}

__device__ __forceinline__ float term4(float4 a, float4 b) {
    return term(a.x, b.x) + term(a.y, b.y) + term(a.z, b.z) + term(a.w, b.w);
}

__global__ __launch_bounds__(NTHREADS) void rmse_partial_kernel(
    const float* __restrict__ in, const float* __restrict__ tg,
    float* __restrict__ partial, int n)
{
    const int n4 = n >> 2;
    const float4* __restrict__ in4 = (const float4*)in;
    const float4* __restrict__ tg4 = (const float4*)tg;

    const int tid  = blockIdx.x * NTHREADS + threadIdx.x;
    const int lane = threadIdx.x & 63;
    const int gw   = tid >> 6;            // global wave id

    // wave-tile: each tile = 256 float4 (4 subtiles of 64); per instruction
    // a wave reads 1KB contiguous (fully coalesced), 8 dwordx4 in flight/thread
    const int ntiles = n4 >> 8;
    float acc0 = 0.f, acc1 = 0.f, acc2 = 0.f, acc3 = 0.f;
    for (int t = gw; t < ntiles; t += TOTAL_WAVES) {
        int base = (t << 8) + lane;
        float4 a0 = in4[base];        float4 b0 = tg4[base];
        float4 a1 = in4[base + 64];   float4 b1 = tg4[base + 64];
        float4 a2 = in4[base + 128];  float4 b2 = tg4[base + 128];
        float4 a3 = in4[base + 192];  float4 b3 = tg4[base + 192];
        acc0 += term4(a0, b0);
        acc1 += term4(a1, b1);
        acc2 += term4(a2, b2);
        acc3 += term4(a3, b3);
    }
    // leftover float4s (n4 % 256)
    for (int i = (ntiles << 8) + tid; i < n4; i += TOTAL_THREADS)
        acc0 += term4(in4[i], tg4[i]);
    // scalar tail (n % 4)
    for (int j = (n4 << 2) + tid; j < n; j += TOTAL_THREADS)
        acc1 += term(in[j], tg[j]);

    float acc = (acc0 + acc1) + (acc2 + acc3);

    #pragma unroll
    for (int off = 32; off > 0; off >>= 1)
        acc += __shfl_down(acc, off, 64);

    __shared__ float smem[NWAVES];
    const int wid = threadIdx.x >> 6;
    if (lane == 0) smem[wid] = acc;
    __syncthreads();

    if (threadIdx.x == 0) {
        float t = 0.f;
        #pragma unroll
        for (int w = 0; w < NWAVES; ++w) t += smem[w];
        partial[blockIdx.x] = t;
    }
}

__global__ __launch_bounds__(NTHREADS) void rmse_final_kernel(
    const float* __restrict__ partial, int nb,
    float* __restrict__ out, float invN)
{
    float acc = 0.0f;
    for (int i = threadIdx.x; i < nb; i += blockDim.x)
        acc += partial[i];

    #pragma unroll
    for (int off = 32; off > 0; off >>= 1)
        acc += __shfl_down(acc, off, 64);

    __shared__ float smem[NWAVES];
    const int lane = threadIdx.x & 63;
    const int wid  = threadIdx.x >> 6;
    if (lane == 0) smem[wid] = acc;
    __syncthreads();

    if (threadIdx.x == 0) {
        float t = 0.0f;
        #pragma unroll
        for (int w = 0; w < NWAVES; ++w) t += smem[w];
        out[0] = sqrtf(t * invN);
    }
}

extern "C" void kernel_launch(void* const* d_in, const int* in_sizes, int n_in,
                              void* d_out, int out_size, void* d_ws, size_t ws_size,
                              hipStream_t stream) {
    const float* inputs  = (const float*)d_in[0];
    const float* targets = (const float*)d_in[1];
    float* out = (float*)d_out;
    float* partial = (float*)d_ws;   // NBLOCKS floats, well under ws_size
    int n = in_sizes[0];

    rmse_partial_kernel<<<NBLOCKS, NTHREADS, 0, stream>>>(inputs, targets, partial, n);
    rmse_final_kernel<<<1, NTHREADS, 0, stream>>>(partial, NBLOCKS, out, 1.0f / (float)n);
}